// Round 2
// baseline (697.362 us; speedup 1.0000x reference)
//
#include <hip/hip_runtime.h>
#include <stdint.h>

#define RESO 192
#define DATA_DIM 28
#define CHUNKS 7   // DATA_DIM / 4
#define NSLAB 16
#define SLABW 12   // RESO / NSLAB

// ---------------- helpers ----------------

__device__ __forceinline__ float4 f4_lerp(float4 a, float4 b, float wa, float wb) {
    float4 r;
    r.x = fmaf(a.x, wa, b.x * wb);
    r.y = fmaf(a.y, wa, b.y * wb);
    r.z = fmaf(a.z, wa, b.z * wb);
    r.w = fmaf(a.w, wa, b.w * wb);
    return r;
}

__device__ __forceinline__ int slab_of(float px, float sx, float ox) {
    float v = fmaf(px, sx, ox);
    v = fminf(fmaxf(v, 0.0f), (float)RESO - 1.0f);
    int lx = (int)v;
    lx = lx > RESO - 2 ? RESO - 2 : lx;   // v >= 0 so trunc == floor; clamp hi
    return lx / SLABW;                    // 0..15
}

// ---------------- pipeline kernels ----------------

__global__ void k_zero(int* __restrict__ hist) {
    if (threadIdx.x < NSLAB) hist[threadIdx.x] = 0;
}

__global__ __launch_bounds__(256) void k_hist(
    const float* __restrict__ points,
    const float* __restrict__ offset,
    const float* __restrict__ scaling,
    int* __restrict__ hist,
    uint8_t* __restrict__ slab8,
    int n)
{
    __shared__ int h[NSLAB];
    if (threadIdx.x < NSLAB) h[threadIdx.x] = 0;
    __syncthreads();
    const int p = blockIdx.x * blockDim.x + threadIdx.x;
    if (p < n) {
        const float sx = scaling[0] * (float)RESO;
        const float ox = offset[0] * (float)RESO - 0.5f;
        const int s = slab_of(points[(size_t)p * 3], sx, ox);
        slab8[p] = (uint8_t)s;
        atomicAdd(&h[s], 1);
    }
    __syncthreads();
    if (threadIdx.x < NSLAB && h[threadIdx.x] > 0)
        atomicAdd(&hist[threadIdx.x], h[threadIdx.x]);
}

__global__ void k_scan(const int* __restrict__ hist, int* __restrict__ cursor) {
    if (threadIdx.x == 0) {
        int run = 0;
        for (int s = 0; s < NSLAB; ++s) { cursor[s] = run; run += hist[s]; }
    }
}

__global__ __launch_bounds__(256) void k_scatter(
    const uint8_t* __restrict__ slab8,
    int* __restrict__ cursor,
    int* __restrict__ perm,
    int n)
{
    __shared__ int h[NSLAB];
    __shared__ int base[NSLAB];
    if (threadIdx.x < NSLAB) h[threadIdx.x] = 0;
    __syncthreads();
    const int p = blockIdx.x * blockDim.x + threadIdx.x;
    int s = 0, slot = 0;
    const bool valid = (p < n);
    if (valid) { s = slab8[p]; slot = atomicAdd(&h[s], 1); }
    __syncthreads();
    if (threadIdx.x < NSLAB) {
        const int c = h[threadIdx.x];
        base[threadIdx.x] = (c > 0) ? atomicAdd(&cursor[threadIdx.x], c) : 0;
    }
    __syncthreads();
    if (valid) perm[base[s] + slot] = p;
}

// ---------------- main sampling kernel (slab-ordered) ----------------

template <bool PERMUTED>
__global__ __launch_bounds__(256) void sparsegrid_sample_kernel(
    const float* __restrict__ points,
    const float* __restrict__ data,
    const int*   __restrict__ links,
    const float* __restrict__ offset,
    const float* __restrict__ scaling,
    const int*   __restrict__ perm,
    float*       __restrict__ out,
    int n_pts)
{
    const int tid = blockIdx.x * blockDim.x + threadIdx.x;
    const int total = n_pts * CHUNKS;
    if (tid >= total) return;

    const int slot = tid / CHUNKS;
    const int c    = tid - slot * CHUNKS;
    const int p    = PERMUTED ? perm[slot] : slot;  // 7 lanes same addr -> broadcast

    int   l[3];
    float wb[3];
#pragma unroll
    for (int i = 0; i < 3; ++i) {
        const float gsz = (float)RESO;
        float v = fmaf(points[(size_t)p * 3 + i], scaling[i] * gsz,
                       offset[i] * gsz - 0.5f);
        v = fminf(fmaxf(v, 0.0f), gsz - 1.0f);
        int li = (int)v;
        li = li < 0 ? 0 : (li > RESO - 2 ? RESO - 2 : li);
        l[i] = li;
        wb[i] = v - (float)li;
    }

    const int dz = 1;
    const int dy = RESO;
    const int dx = RESO * RESO;
    const int base = (l[0] * RESO + l[1]) * RESO + l[2];

    int lk[8];
    lk[0] = links[base];
    lk[1] = links[base + dz];
    lk[2] = links[base + dy];
    lk[3] = links[base + dy + dz];
    lk[4] = links[base + dx];
    lk[5] = links[base + dx + dz];
    lk[6] = links[base + dx + dy];
    lk[7] = links[base + dx + dy + dz];

    float4 cv[8];
#pragma unroll
    for (int k = 0; k < 8; ++k) {
        const int idx = lk[k] < 0 ? 0 : lk[k];
        cv[k] = *reinterpret_cast<const float4*>(
            data + (size_t)idx * DATA_DIM + (size_t)c * 4);
    }
#pragma unroll
    for (int k = 0; k < 8; ++k) {
        if (lk[k] < 0) cv[k] = make_float4(0.f, 0.f, 0.f, 0.f);
    }

    const float waz = 1.0f - wb[2], wbz = wb[2];
    const float way = 1.0f - wb[1], wby = wb[1];
    const float wax = 1.0f - wb[0], wbx = wb[0];

    float4 c00 = f4_lerp(cv[0], cv[1], waz, wbz);
    float4 c01 = f4_lerp(cv[2], cv[3], waz, wbz);
    float4 c10 = f4_lerp(cv[4], cv[5], waz, wbz);
    float4 c11 = f4_lerp(cv[6], cv[7], waz, wbz);

    float4 c0 = f4_lerp(c00, c01, way, wby);
    float4 c1 = f4_lerp(c10, c11, way, wby);
    float4 s  = f4_lerp(c0, c1, wax, wbx);

    // output location belongs to the ORIGINAL point index p
    *reinterpret_cast<float4*>(out + (size_t)p * DATA_DIM + (size_t)c * 4) = s;
}

// ---------------- launch ----------------

extern "C" void kernel_launch(void* const* d_in, const int* in_sizes, int n_in,
                              void* d_out, int out_size, void* d_ws, size_t ws_size,
                              hipStream_t stream)
{
    const float* points  = (const float*)d_in[0];
    const float* data    = (const float*)d_in[1];
    const int*   links   = (const int*)d_in[2];
    const float* offset  = (const float*)d_in[3];
    const float* scaling = (const float*)d_in[4];
    float*       out     = (float*)d_out;

    const int n_pts = in_sizes[0] / 3;
    const int total = n_pts * CHUNKS;
    const int block = 256;

    // ws layout: [0,64) hist | [128,192) cursor | [1024, 1024+4n) perm | then slab8[n]
    const size_t need = 1024 + (size_t)n_pts * 4 + (size_t)n_pts;

    if (ws_size >= need) {
        int*     hist   = (int*)d_ws;
        int*     cursor = (int*)((char*)d_ws + 128);
        int*     perm   = (int*)((char*)d_ws + 1024);
        uint8_t* slab8  = (uint8_t*)((char*)d_ws + 1024 + (size_t)n_pts * 4);

        const int gpts = (n_pts + block - 1) / block;

        k_zero<<<1, 64, 0, stream>>>(hist);
        k_hist<<<gpts, block, 0, stream>>>(points, offset, scaling, hist, slab8, n_pts);
        k_scan<<<1, 64, 0, stream>>>(hist, cursor);
        k_scatter<<<gpts, block, 0, stream>>>(slab8, cursor, perm, n_pts);
        sparsegrid_sample_kernel<true><<<(total + block - 1) / block, block, 0, stream>>>(
            points, data, links, offset, scaling, perm, out, n_pts);
    } else {
        sparsegrid_sample_kernel<false><<<(total + block - 1) / block, block, 0, stream>>>(
            points, data, links, offset, scaling, (const int*)nullptr, out, n_pts);
    }
}